// Round 11
// baseline (291.270 us; speedup 1.0000x reference)
//
#include <hip/hip_runtime.h>

// Problem constants: B=2, C=256, P=64 (NH=4, HD=16), H=W=64 -> N=4096, G=16.
#define B_ 2
#define C_ 256
#define P_ 64
#define N_ 4096
#define EPS_ 1e-5f
// SCALE * log2(e): softmax computed in exp2 domain (folded into q)
#define QSCALE_ 0.3606737602222409f

typedef _Float16 half4 __attribute__((ext_vector_type(4)));
typedef _Float16 half8 __attribute__((ext_vector_type(8)));
typedef float f32x4 __attribute__((ext_vector_type(4)));

// Schraudolph fast exp2 (validated R8-R10: absmax unchanged).
static __device__ __forceinline__ float fexp2(float x) {
  return __builtin_bit_cast(float, (int)fmaf(x, 8388608.0f, 1064872512.0f));
}

struct TP {
  const float* feat[3];
  const float* Wq[3]; const float* bq[3];
  const float* Wk[3]; const float* bk[3];
  const float* Wv[3]; const float* bv[3];
  const float* Wo[3]; const float* bo[3];
  const float* gm[3]; const float* bt[3];
  _Float16* q16;   // [3][2][4096][64]  scaled q
  _Float16* kp0;   // [3][8(b4h)][4096][16] K partial from ctx slot 0 (no bias)
  _Float16* kp1;   // slot 1
  _Float16* vp0;   // [3][8][16][4096]      V partial slot 0 (no bias)
  _Float16* vp1;
  _Float16* ao0;   // [3][2][4096][64]  unnormalized O, kv-half 0
  _Float16* ao1;
  float* L;        // [2][3][8(bh)][4096] softmax partial denominators
  float* stats;    // [3][2][16][2] {sum, sumsq}
  float* out;
};

// ---------------------------------------------------------------------------
// Split-K projection: one block per (source feat mp, b, 32n tile). Stages
// the fp32 feat tile ONCE (32n x 256c -> LDS f16), then computes:
//   - Q[mp] (bias+QSCALE applied)
//   - K/V partials of feat[mp] for its two consumer modalities (biasless;
//     combined in attn staging). Feat global reads: 72 MB -> 24 MB.
// grid (128, 2, 3), block 256 (wave w = head w).
// ---------------------------------------------------------------------------
#define PST_ 264  // feat-tile LDS row stride (halfs)

__global__ __launch_bounds__(256) void proj_split_kernel(TP P) {
  __shared__ _Float16 bs[32 * PST_];  // 16,896 B feat tile
  __shared__ _Float16 vt[64 * 40];    // 5,120 B V-transpose buffer
  const int mp = blockIdx.z, b = blockIdx.y;
  const int n0 = blockIdx.x * 32;
  const int tid = threadIdx.x;
  const int w = tid >> 6, g = (tid >> 4) & 3, t = tid & 15;

  // ---- stage feat[mp] tile ----
  {
    const int sn = tid & 31;
    const int cb = (tid >> 5) * 32;
    const float* __restrict__ in = P.feat[mp] + (size_t)b * C_ * N_ + n0 + sn;
    float f[32];
#pragma unroll
    for (int i = 0; i < 32; ++i) f[i] = in[(size_t)(cb + i) * N_];
#pragma unroll
    for (int j = 0; j < 4; ++j) {
      half8 h;
#pragma unroll
      for (int r = 0; r < 8; ++r) h[r] = (_Float16)f[j * 8 + r];
      *(half8*)(bs + sn * PST_ + cb + j * 8) = h;
    }
  }
  __syncthreads();

  // ---- Q projection for mp ----
  {
    f32x4 a[2] = {{0.f,0.f,0.f,0.f},{0.f,0.f,0.f,0.f}};
    const float* __restrict__ Wq = P.Wq[mp] + (w * 16 + t) * 256;
#pragma unroll
    for (int ks = 0; ks < 8; ++ks) {
      const float4 w0 = *(const float4*)(Wq + ks * 32 + g * 8);
      const float4 w1 = *(const float4*)(Wq + ks * 32 + g * 8 + 4);
      half8 af;
      af[0] = (_Float16)w0.x; af[1] = (_Float16)w0.y;
      af[2] = (_Float16)w0.z; af[3] = (_Float16)w0.w;
      af[4] = (_Float16)w1.x; af[5] = (_Float16)w1.y;
      af[6] = (_Float16)w1.z; af[7] = (_Float16)w1.w;
#pragma unroll
      for (int i = 0; i < 2; ++i) {
        const half8 bf = *(const half8*)(bs + (i * 16 + t) * PST_ + ks * 32 + g * 8);
        a[i] = __builtin_amdgcn_mfma_f32_16x16x32_f16(af, bf, a[i], 0, 0, 0);
      }
    }
    _Float16* qo = P.q16 + ((size_t)(mp * 2 + b) * N_) * 64 + w * 16 + g * 4;
#pragma unroll
    for (int i = 0; i < 2; ++i) {
      half4 hq;
#pragma unroll
      for (int r = 0; r < 4; ++r) {
        const float bq = P.bq[mp][w * 16 + g * 4 + r];
        hq[r] = (_Float16)((a[i][r] + bq) * QSCALE_);
      }
      *(half4*)(qo + (size_t)(n0 + i * 16 + t) * 64) = hq;
    }
  }

  // ---- K/V partials for the two consumer modalities ----
  // consumer modality and its ctx-slot for this producer:
  const int consM[3][2] = {{1, 2}, {0, 2}, {0, 1}};
  const int consS[3][2] = {{0, 0}, {0, 1}, {1, 1}};
#pragma unroll
  for (int ci = 0; ci < 2; ++ci) {
    const int m = consM[mp][ci], s = consS[mp][ci];
    f32x4 ka[2] = {{0.f,0.f,0.f,0.f},{0.f,0.f,0.f,0.f}};
    f32x4 va[2] = {{0.f,0.f,0.f,0.f},{0.f,0.f,0.f,0.f}};
    const float* __restrict__ Wk = P.Wk[m] + (w * 16 + t) * 512 + s * 256;
    const float* __restrict__ Wv = P.Wv[m] + (w * 16 + t) * 512 + s * 256;
#pragma unroll
    for (int ks = 0; ks < 8; ++ks) {
      const float4 k0 = *(const float4*)(Wk + ks * 32 + g * 8);
      const float4 k1 = *(const float4*)(Wk + ks * 32 + g * 8 + 4);
      const float4 v0 = *(const float4*)(Wv + ks * 32 + g * 8);
      const float4 v1 = *(const float4*)(Wv + ks * 32 + g * 8 + 4);
      half8 ak, av;
      ak[0] = (_Float16)k0.x; ak[1] = (_Float16)k0.y;
      ak[2] = (_Float16)k0.z; ak[3] = (_Float16)k0.w;
      ak[4] = (_Float16)k1.x; ak[5] = (_Float16)k1.y;
      ak[6] = (_Float16)k1.z; ak[7] = (_Float16)k1.w;
      av[0] = (_Float16)v0.x; av[1] = (_Float16)v0.y;
      av[2] = (_Float16)v0.z; av[3] = (_Float16)v0.w;
      av[4] = (_Float16)v1.x; av[5] = (_Float16)v1.y;
      av[6] = (_Float16)v1.z; av[7] = (_Float16)v1.w;
#pragma unroll
      for (int i = 0; i < 2; ++i) {
        const half8 bf = *(const half8*)(bs + (i * 16 + t) * PST_ + ks * 32 + g * 8);
        ka[i] = __builtin_amdgcn_mfma_f32_16x16x32_f16(ak, bf, ka[i], 0, 0, 0);
        va[i] = __builtin_amdgcn_mfma_f32_16x16x32_f16(av, bf, va[i], 0, 0, 0);
      }
    }
    // K partial: direct half4 stores
    _Float16* ko = (s ? P.kp1 : P.kp0) +
                   ((size_t)(m * 8 + b * 4 + w) * N_) * 16 + g * 4;
#pragma unroll
    for (int i = 0; i < 2; ++i) {
      half4 hk;
#pragma unroll
      for (int r = 0; r < 4; ++r) hk[r] = (_Float16)ka[i][r];
      *(half4*)(ko + (size_t)(n0 + i * 16 + t) * 16) = hk;
    }
    // V partial: transpose through LDS, 16B coalesced stores
    __syncthreads();  // prior vt reads (ci-1) done
#pragma unroll
    for (int i = 0; i < 2; ++i)
#pragma unroll
      for (int r = 0; r < 4; ++r)
        vt[(w * 16 + g * 4 + r) * 40 + i * 16 + t] = (_Float16)va[i][r];
    __syncthreads();
    const int row = tid >> 2, nb = (tid & 3) * 8;
    const half8 hv = *(const half8*)(vt + row * 40 + nb);
    _Float16* vo = (s ? P.vp1 : P.vp0) +
                   ((size_t)(m * 8 + b * 4 + (row >> 4)) * 16 + (row & 15)) * N_;
    *(half8*)(vo + n0 + nb) = hv;
  }
}

// ---------------------------------------------------------------------------
// MFMA flash attention, split-kv x2. Staging combines the two K/V partials
// + bias (packed f16 adds) -- the split-K reduction rides the LDS staging.
// ks stride 24 (bank-volume floor), vs XOR-swizzled. Static softmax in exp2
// domain; writes UNNORMALIZED O to ao0/ao1 + partial l to L.
// grid (64, 8, 3): x = qb*2 + kv-half. block 512 (8 waves).
// ---------------------------------------------------------------------------
#define KST_ 24

__global__ __launch_bounds__(512) void attn_kernel(TP P) {
  const int m = blockIdx.z, bh = blockIdx.y;
  const int tid = threadIdx.x;
  if (m == 0 && bh == 0 && blockIdx.x == 0 && tid < 192) P.stats[tid] = 0.f;
  const int kvh = blockIdx.x & 1, qb = blockIdx.x >> 1;
  const int kvbase = kvh * 2048;
  const int w = tid >> 6, g = (tid >> 4) & 3, t = tid & 15;
  const int b = bh >> 2, h = bh & 3;
  const size_t khb = ((size_t)(m * 8 + bh) * N_) * 16;
  const size_t vhb = ((size_t)(m * 8 + bh) * 16) * N_;
  const _Float16* __restrict__ qh =
      P.q16 + ((size_t)(m * 2 + b) * N_) * 64 + h * 16 + g * 4;

  const int q0 = qb * 128 + w * 16;
  const half4 qf = *(const half4*)(qh + (size_t)(q0 + t) * 64);

  __shared__ _Float16 ks[256 * KST_];
  __shared__ _Float16 vs[16 * 256];

  const int kr = tid >> 1, kc8 = tid & 1;   // K: 256 rows x 2 half8
  const int vr = tid >> 5, vc = tid & 31;   // V: 16 rows x 32 half8
  const size_t koff = khb + (size_t)(kvbase + kr) * 16 + kc8 * 8;
  const size_t voff = vhb + (size_t)vr * N_ + kvbase + vc * 8;
  const _Float16* kg0 = P.kp0 + koff;
  const _Float16* kg1 = P.kp1 + koff;
  const _Float16* vg0 = P.vp0 + voff;
  const _Float16* vg1 = P.vp1 + voff;
  _Float16* ksp = ks + kr * KST_ + kc8 * 8;
  _Float16* vsp = vs + vr * 256 + ((vc ^ vr) << 3);

  // bias vectors for this thread's staging slice
  half8 bk8, bv8;
#pragma unroll
  for (int j = 0; j < 8; ++j) {
    bk8[j] = (_Float16)P.bk[m][h * 16 + kc8 * 8 + j];
    bv8[j] = (_Float16)P.bv[m][h * 16 + vr];
  }

  half8 kpre = *(const half8*)kg0 + *(const half8*)kg1 + bk8;
  half8 vpre = *(const half8*)vg0 + *(const half8*)vg1 + bv8;

  f32x4 lacc = {0.f, 0.f, 0.f, 0.f};
  f32x4 O0 = {0.f,0.f,0.f,0.f}, O1 = {0.f,0.f,0.f,0.f};

  for (int c0 = 0; c0 < 2048; c0 += 256) {
    *(half8*)ksp = kpre;
    *(half8*)vsp = vpre;
    __syncthreads();
    const int nxt = (c0 + 256 < 2048) ? c0 + 256 : 0;
    kpre = *(const half8*)(kg0 + (size_t)nxt * 16) +
           *(const half8*)(kg1 + (size_t)nxt * 16) + bk8;
    vpre = *(const half8*)(vg0 + nxt) + *(const half8*)(vg1 + nxt) + bv8;
#pragma unroll
    for (int hc = 0; hc < 4; ++hc) {
      f32x4 s[4];
#pragma unroll
      for (int i = 0; i < 4; ++i) {
        const int sub = hc * 4 + i;
        const half4 kf = *(const half4*)(ks + (sub * 16 + t) * KST_ +
                                         (g >> 1) * 8 + (g & 1) * 4);
        const f32x4 z = {0.f, 0.f, 0.f, 0.f};
        s[i] = __builtin_amdgcn_mfma_f32_16x16x16f16(kf, qf, z, 0, 0, 0);
      }
      half4 pf[4];
#pragma unroll
      for (int i = 0; i < 4; ++i) {
        const float p0 = fexp2(s[i][0]), p1 = fexp2(s[i][1]);
        const float p2 = fexp2(s[i][2]), p3 = fexp2(s[i][3]);
        lacc[0] += p0; lacc[1] += p1; lacc[2] += p2; lacc[3] += p3;
        pf[i][0] = (_Float16)p0; pf[i][1] = (_Float16)p1;
        pf[i][2] = (_Float16)p2; pf[i][3] = (_Float16)p3;
      }
#pragma unroll
      for (int i = 0; i < 4; ++i) {
        const int c = (hc * 4 + i) * 2 + (g >> 1);
        const half4 vf = *(const half4*)(vs + t * 256 + ((c ^ t) << 3) + (g & 1) * 4);
        if (i & 1) O1 = __builtin_amdgcn_mfma_f32_16x16x16f16(vf, pf[i], O1, 0, 0, 0);
        else       O0 = __builtin_amdgcn_mfma_f32_16x16x16f16(vf, pf[i], O0, 0, 0, 0);
      }
    }
    __syncthreads();
  }
  float l = lacc[0] + lacc[1] + lacc[2] + lacc[3];
  l += __shfl_xor(l, 16);
  l += __shfl_xor(l, 32);
  _Float16* aop = (kvh ? P.ao1 : P.ao0) +
                  ((size_t)(m * 2 + b) * N_ + q0 + t) * 64 + h * 16 + g * 4;
  half4 hv;
#pragma unroll
  for (int r = 0; r < 4; ++r) hv[r] = (_Float16)(O0[r] + O1[r]);
  *(half4*)aop = hv;
  if ((tid & 48) == 0)
    P.L[((size_t)(kvh * 3 + m) * 8 + bh) * N_ + q0 + t] = l;
}

// ---------------------------------------------------------------------------
// Wo projection + bias + residual -> d_out, fused GroupNorm stats.
// Stages ao0+ao1 (summed) in LDS; lane-uniform 1/(l0+l1) applied pre-MFMA.
// grid (64, 8, 3).
// ---------------------------------------------------------------------------
#define BS_ 72

__global__ __launch_bounds__(256) void wo_resid_kernel(TP P) {
  __shared__ _Float16 as[64 * BS_];
  const int m = blockIdx.z;
  const int b = blockIdx.y >> 2, cblk = blockIdx.y & 3;
  const int n0 = blockIdx.x * 64;
  const int tid = threadIdx.x;
  const int w = tid >> 6, g = (tid >> 4) & 3, t = tid & 15;
  const int c0 = cblk * 64 + w * 16;
  const size_t aob = ((size_t)(m * 2 + b) * N_) * 64;
  const _Float16* __restrict__ a0p = P.ao0 + aob;
  const _Float16* __restrict__ a1p = P.ao1 + aob;
  const int ar = tid >> 2, ac = (tid & 3) * 16;
  {
    const size_t off = (size_t)(n0 + ar) * 64 + ac;
    half8 s0 = *(const half8*)(a0p + off);
    half8 s1 = *(const half8*)(a0p + off + 8);
    const half8 u0 = *(const half8*)(a1p + off);
    const half8 u1 = *(const half8*)(a1p + off + 8);
    s0 += u0; s1 += u1;
    *(half8*)(as + ar * BS_ + ac) = s0;
    *(half8*)(as + ar * BS_ + ac + 8) = s1;
  }
  __syncthreads();
  const float* __restrict__ L0 = P.L + ((size_t)m * 8 + b * 4) * N_;
  const float* __restrict__ L1 = P.L + ((size_t)(3 + m) * 8 + b * 4) * N_;
  f32x4 acc[4] = {{0.f,0.f,0.f,0.f},{0.f,0.f,0.f,0.f},{0.f,0.f,0.f,0.f},{0.f,0.f,0.f,0.f}};
  const float* __restrict__ Wo = P.Wo[m] + (c0 + t) * 64;
#pragma unroll
  for (int kst = 0; kst < 2; ++kst) {
    const float4 w0 = *(const float4*)(Wo + kst * 32 + g * 8);
    const float4 w1 = *(const float4*)(Wo + kst * 32 + g * 8 + 4);
    half8 a;
    a[0] = (_Float16)w0.x; a[1] = (_Float16)w0.y;
    a[2] = (_Float16)w0.z; a[3] = (_Float16)w0.w;
    a[4] = (_Float16)w1.x; a[5] = (_Float16)w1.y;
    a[6] = (_Float16)w1.z; a[7] = (_Float16)w1.w;
    const int head = kst * 2 + (g >> 1);
#pragma unroll
    for (int i = 0; i < 4; ++i) {
      const int n = n0 + i * 16 + t;
      half8 bf = *(const half8*)(as + (i * 16 + t) * BS_ + kst * 32 + g * 8);
      const float ls = L0[(size_t)head * N_ + n] + L1[(size_t)head * N_ + n];
      const _Float16 hs = (_Float16)(1.0f / ls);
#pragma unroll
      for (int r = 0; r < 8; ++r) bf[r] *= hs;
      acc[i] = __builtin_amdgcn_mfma_f32_16x16x32_f16(a, bf, acc[i], 0, 0, 0);
    }
  }
  const float* __restrict__ X = P.feat[m] + (size_t)b * C_ * N_;
  float* outb = P.out + (size_t)m * B_ * C_ * N_ + (size_t)b * C_ * N_;
  float s = 0.f, s2 = 0.f;
#pragma unroll
  for (int i = 0; i < 4; ++i) {
    const int n = n0 + i * 16 + t;
#pragma unroll
    for (int r = 0; r < 4; ++r) {
      const int c = c0 + g * 4 + r;
      const float val = acc[i][r] + X[(size_t)c * N_ + n] + P.bo[m][c];
      outb[(size_t)c * N_ + n] = val;
      s += val;
      s2 += val * val;
    }
  }
#pragma unroll
  for (int off = 1; off < 64; off <<= 1) {
    s += __shfl_xor(s, off);
    s2 += __shfl_xor(s2, off);
  }
  if ((tid & 63) == 0) {
    const int group = cblk * 4 + w;
    float* st = P.stats + ((size_t)(m * 2 + b) * 16 + group) * 2;
    atomicAdd(st, s);
    atomicAdd(st + 1, s2);
  }
}

// ---------------------------------------------------------------------------
// GroupNorm normalize pass, 4 float4 per thread. grid (1536), block 256.
// ---------------------------------------------------------------------------
__global__ __launch_bounds__(256) void gn_final_kernel(TP P) {
  const size_t base = ((size_t)blockIdx.x * 256 + threadIdx.x) * 4;
#pragma unroll
  for (int it = 0; it < 4; ++it) {
    const size_t idx = base + (size_t)it * 1572864;
    const int m = (int)(idx >> 21);
    const int rem = (int)(idx & ((1u << 21) - 1));
    const int b = rem >> 20;
    const int c = (rem >> 12) & 255;
    const float* st = P.stats + ((size_t)(m * 2 + b) * 16 + (c >> 4)) * 2;
    const float mean = st[0] * (1.f / 65536.f);
    const float var = st[1] * (1.f / 65536.f) - mean * mean;
    const float rstd = rsqrtf(var + EPS_);
    const float ga = P.gm[m][c] * rstd, be = P.bt[m][c];
    float4 x = *(float4*)(P.out + idx);
    x.x = (x.x - mean) * ga + be;
    x.y = (x.y - mean) * ga + be;
    x.z = (x.z - mean) * ga + be;
    x.w = (x.w - mean) * ga + be;
    *(float4*)(P.out + idx) = x;
  }
}

// ---------------------------------------------------------------------------
extern "C" void kernel_launch(void* const* d_in, const int* in_sizes, int n_in,
                              void* d_out, int out_size, void* d_ws, size_t ws_size,
                              hipStream_t stream) {
  TP P;
  for (int m = 0; m < 3; ++m) {
    P.feat[m] = (const float*)d_in[m];
    const int base = 3 + m * 10;
    P.Wq[m] = (const float*)d_in[base + 0];
    P.bq[m] = (const float*)d_in[base + 1];
    P.Wk[m] = (const float*)d_in[base + 2];
    P.bk[m] = (const float*)d_in[base + 3];
    P.Wv[m] = (const float*)d_in[base + 4];
    P.bv[m] = (const float*)d_in[base + 5];
    P.Wo[m] = (const float*)d_in[base + 6];
    P.bo[m] = (const float*)d_in[base + 7];
    P.gm[m] = (const float*)d_in[base + 8];
    P.bt[m] = (const float*)d_in[base + 9];
  }
  _Float16* ws = (_Float16*)d_ws;
  const size_t SZ = 1572864;  // halfs per [3][2][4096][64]-class buffer
  P.q16 = ws;
  P.kp0 = ws + SZ;
  P.kp1 = ws + 2 * SZ;
  P.vp0 = ws + 3 * SZ;
  P.vp1 = ws + 4 * SZ;
  P.ao0 = ws + 5 * SZ;
  P.ao1 = ws + 6 * SZ;
  P.L = (float*)(ws + 7 * SZ);            // 196,608 floats
  P.stats = (float*)(ws + 7 * SZ) + 196608;
  P.out = (float*)d_out;

  proj_split_kernel<<<dim3(128, 2, 3), dim3(256), 0, stream>>>(P);
  attn_kernel<<<dim3(64, 8, 3), dim3(512), 0, stream>>>(P);
  wo_resid_kernel<<<dim3(64, 8, 3), dim3(256), 0, stream>>>(P);
  gn_final_kernel<<<dim3(1536), dim3(256), 0, stream>>>(P);
}

// Round 12
// 278.836 us; speedup vs baseline: 1.0446x; 1.0446x over previous
//
#include <hip/hip_runtime.h>

// Problem constants: B=2, C=256, P=64 (NH=4, HD=16), H=W=64 -> N=4096, G=16.
#define B_ 2
#define C_ 256
#define P_ 64
#define N_ 4096
#define EPS_ 1e-5f
// SCALE * log2(e): softmax computed in exp2 domain (folded into q)
#define QSCALE_ 0.3606737602222409f

typedef _Float16 half4 __attribute__((ext_vector_type(4)));
typedef _Float16 half8 __attribute__((ext_vector_type(8)));
typedef float f32x4 __attribute__((ext_vector_type(4)));

// Schraudolph fast exp2 (validated R8-R11: absmax unchanged).
static __device__ __forceinline__ float fexp2(float x) {
  return __builtin_bit_cast(float, (int)fmaf(x, 8388608.0f, 1064872512.0f));
}

struct TP {
  const float* feat[3];
  const float* Wq[3]; const float* bq[3];
  const float* Wk[3]; const float* bk[3];
  const float* Wv[3]; const float* bv[3];
  const float* Wo[3]; const float* bo[3];
  const float* gm[3]; const float* bt[3];
  _Float16* q16;   // [3][2][4096][64]  scaled q
  _Float16* k16;   // [3][8(b4h)][4096][16]
  _Float16* v16;   // [3][8][16][4096]
  _Float16* ao0;   // [3][2][4096][64]  unnormalized O, kv-half 0
  _Float16* ao1;   // kv-half 1
  float* L;        // [2][3][8(bh)][4096] softmax partial denominators
  float* stats;    // [3][2][16][2] {sum, sumsq}
  float* out;
  int ctx0[3]; int ctx1[3];
};

// ---------------------------------------------------------------------------
// Fused projection (R10 form): stages 64n x 256c fp32 feat tile -> LDS f16
// [n][c]; W fragments converted fp32->f16 in registers (L2-hot).
// grid (128, 2, 3): x<64 KV (K=512 both ctx feats), x>=64 Q. block 256.
// ---------------------------------------------------------------------------
#define PST_ 264
#define VTS_ 88

__global__ __launch_bounds__(256) void proj_fused_kernel(TP P) {
  __shared__ _Float16 bs[64 * PST_];
  const int m = blockIdx.z, b = blockIdx.y;
  const int tid = threadIdx.x;
  const int w = tid >> 6, g = (tid >> 4) & 3, t = tid & 15;
  const bool is_q = blockIdx.x >= 64;
  const int n0 = (is_q ? blockIdx.x - 64 : (int)blockIdx.x) * 64;
  const int sn = tid & 63, scb = (tid >> 6) * 16;

  if (is_q) {
    const float* __restrict__ in = P.feat[m] + (size_t)b * C_ * N_ + n0 + sn;
#pragma unroll
    for (int cc = 0; cc < 4; ++cc) {
      const int c0 = cc * 64 + scb;
      float f[16];
#pragma unroll
      for (int i = 0; i < 16; ++i) f[i] = in[(size_t)(c0 + i) * N_];
      half8 h0, h1;
#pragma unroll
      for (int j = 0; j < 8; ++j) { h0[j] = (_Float16)f[j]; h1[j] = (_Float16)f[8 + j]; }
      *(half8*)(bs + sn * PST_ + c0) = h0;
      *(half8*)(bs + sn * PST_ + c0 + 8) = h1;
    }
    __syncthreads();
    f32x4 a[4] = {{0.f,0.f,0.f,0.f},{0.f,0.f,0.f,0.f},{0.f,0.f,0.f,0.f},{0.f,0.f,0.f,0.f}};
    const float* __restrict__ Wq = P.Wq[m] + (w * 16 + t) * 256;
#pragma unroll
    for (int ks = 0; ks < 8; ++ks) {
      const float4 wa = *(const float4*)(Wq + ks * 32 + g * 8);
      const float4 wb = *(const float4*)(Wq + ks * 32 + g * 8 + 4);
      half8 af;
      af[0] = (_Float16)wa.x; af[1] = (_Float16)wa.y;
      af[2] = (_Float16)wa.z; af[3] = (_Float16)wa.w;
      af[4] = (_Float16)wb.x; af[5] = (_Float16)wb.y;
      af[6] = (_Float16)wb.z; af[7] = (_Float16)wb.w;
#pragma unroll
      for (int i = 0; i < 4; ++i) {
        const half8 bf = *(const half8*)(bs + (i * 16 + t) * PST_ + ks * 32 + g * 8);
        a[i] = __builtin_amdgcn_mfma_f32_16x16x32_f16(af, bf, a[i], 0, 0, 0);
      }
    }
    float bq[4];
#pragma unroll
    for (int r = 0; r < 4; ++r) bq[r] = P.bq[m][w * 16 + g * 4 + r];
    _Float16* qo = P.q16 + ((size_t)(m * 2 + b) * N_) * 64 + w * 16 + g * 4;
#pragma unroll
    for (int i = 0; i < 4; ++i) {
      half4 hq;
#pragma unroll
      for (int r = 0; r < 4; ++r) hq[r] = (_Float16)((a[i][r] + bq[r]) * QSCALE_);
      *(half4*)(qo + (size_t)(n0 + i * 16 + t) * 64) = hq;
    }
  } else {
    f32x4 ka[4] = {{0.f,0.f,0.f,0.f},{0.f,0.f,0.f,0.f},{0.f,0.f,0.f,0.f},{0.f,0.f,0.f,0.f}};
    f32x4 va[4] = {{0.f,0.f,0.f,0.f},{0.f,0.f,0.f,0.f},{0.f,0.f,0.f,0.f},{0.f,0.f,0.f,0.f}};
    const int srcs[2] = {P.ctx0[m], P.ctx1[m]};
    for (int src = 0; src < 2; ++src) {
      const float* __restrict__ in =
          P.feat[srcs[src]] + (size_t)b * C_ * N_ + n0 + sn;
      if (src) __syncthreads();
#pragma unroll
      for (int cc = 0; cc < 4; ++cc) {
        const int c0 = cc * 64 + scb;
        float f[16];
#pragma unroll
        for (int i = 0; i < 16; ++i) f[i] = in[(size_t)(c0 + i) * N_];
        half8 h0, h1;
#pragma unroll
        for (int j = 0; j < 8; ++j) { h0[j] = (_Float16)f[j]; h1[j] = (_Float16)f[8 + j]; }
        *(half8*)(bs + sn * PST_ + c0) = h0;
        *(half8*)(bs + sn * PST_ + c0 + 8) = h1;
      }
      __syncthreads();
      const float* __restrict__ Wk = P.Wk[m] + (w * 16 + t) * 512 + src * 256;
      const float* __restrict__ Wv = P.Wv[m] + (w * 16 + t) * 512 + src * 256;
#pragma unroll
      for (int ks = 0; ks < 8; ++ks) {
        const float4 k0 = *(const float4*)(Wk + ks * 32 + g * 8);
        const float4 k1 = *(const float4*)(Wk + ks * 32 + g * 8 + 4);
        const float4 v0 = *(const float4*)(Wv + ks * 32 + g * 8);
        const float4 v1 = *(const float4*)(Wv + ks * 32 + g * 8 + 4);
        half8 ak, av;
        ak[0] = (_Float16)k0.x; ak[1] = (_Float16)k0.y;
        ak[2] = (_Float16)k0.z; ak[3] = (_Float16)k0.w;
        ak[4] = (_Float16)k1.x; ak[5] = (_Float16)k1.y;
        ak[6] = (_Float16)k1.z; ak[7] = (_Float16)k1.w;
        av[0] = (_Float16)v0.x; av[1] = (_Float16)v0.y;
        av[2] = (_Float16)v0.z; av[3] = (_Float16)v0.w;
        av[4] = (_Float16)v1.x; av[5] = (_Float16)v1.y;
        av[6] = (_Float16)v1.z; av[7] = (_Float16)v1.w;
#pragma unroll
        for (int i = 0; i < 4; ++i) {
          const half8 bf = *(const half8*)(bs + (i * 16 + t) * PST_ + ks * 32 + g * 8);
          ka[i] = __builtin_amdgcn_mfma_f32_16x16x32_f16(ak, bf, ka[i], 0, 0, 0);
          va[i] = __builtin_amdgcn_mfma_f32_16x16x32_f16(av, bf, va[i], 0, 0, 0);
        }
      }
    }
    float bk[4], bv[4];
#pragma unroll
    for (int r = 0; r < 4; ++r) {
      bk[r] = P.bk[m][w * 16 + g * 4 + r];
      bv[r] = P.bv[m][w * 16 + g * 4 + r];
    }
    _Float16* ko = P.k16 + ((size_t)(m * 8 + b * 4 + w) * N_) * 16 + g * 4;
#pragma unroll
    for (int i = 0; i < 4; ++i) {
      half4 hk;
#pragma unroll
      for (int r = 0; r < 4; ++r) hk[r] = (_Float16)(ka[i][r] + bk[r]);
      *(half4*)(ko + (size_t)(n0 + i * 16 + t) * 16) = hk;
    }
    __syncthreads();
#pragma unroll
    for (int i = 0; i < 4; ++i)
#pragma unroll
      for (int r = 0; r < 4; ++r)
        bs[(w * 16 + g * 4 + r) * VTS_ + i * 16 + t] = (_Float16)(va[i][r] + bv[r]);
    __syncthreads();
#pragma unroll
    for (int pass = 0; pass < 2; ++pass) {
      const int row = pass * 32 + (tid >> 3);
      const int hh = row >> 4, dd = row & 15, nb = (tid & 7) * 8;
      const half8 hv = *(const half8*)(bs + row * VTS_ + nb);
      *(half8*)(P.v16 + ((size_t)(m * 8 + b * 4 + hh) * 16 + dd) * N_ + n0 + nb) = hv;
    }
  }
}

// ---------------------------------------------------------------------------
// MFMA flash attention: R6 geometry (256-thr blocks, wave = 16q, block =
// 64q, VGPR ~50 -> 8 waves/SIMD) + R10's wins (KST=24 bank-floor K layout,
// split-kv x2, Schraudolph). kv-chunk 128: exactly one half8 per thread per
// buffer for staging. Writes UNNORMALIZED O + partial l; wo combines.
// grid (128, 8, 3): x = qb*2 + kv-half. block 256.
// ---------------------------------------------------------------------------
#define KST_ 24

__global__ __launch_bounds__(256) void attn_kernel(TP P) {
  const int m = blockIdx.z, bh = blockIdx.y;
  const int tid = threadIdx.x;
  if (m == 0 && bh == 0 && blockIdx.x == 0 && tid < 192) P.stats[tid] = 0.f;
  const int kvh = blockIdx.x & 1, qb = blockIdx.x >> 1;
  const int kvbase = kvh * 2048;
  const int w = tid >> 6, g = (tid >> 4) & 3, t = tid & 15;
  const int b = bh >> 2, h = bh & 3;
  const _Float16* __restrict__ kh = P.k16 + ((size_t)(m * 8 + bh) * N_) * 16;
  const _Float16* __restrict__ vh = P.v16 + ((size_t)(m * 8 + bh) * 16) * N_;
  const _Float16* __restrict__ qh =
      P.q16 + ((size_t)(m * 2 + b) * N_) * 64 + h * 16 + g * 4;

  const int q0 = qb * 64 + w * 16;
  const half4 qf = *(const half4*)(qh + (size_t)(q0 + t) * 64);

  __shared__ _Float16 ks[128 * KST_];  // [kv][d] stride 24 -> bank floor
  __shared__ _Float16 vs[16 * 128];    // [d][kv], XOR-swizzled (floor)

  const int kr = tid >> 1, kc8 = tid & 1;   // K: 128 rows x 2 half8
  const int vr = tid >> 4, vc = tid & 15;   // V: 16 rows x 16 half8
  const _Float16* kgp = kh + (size_t)(kvbase + kr) * 16 + kc8 * 8;
  const _Float16* vgp = vh + (size_t)vr * N_ + kvbase + vc * 8;
  _Float16* ksp = ks + kr * KST_ + kc8 * 8;
  _Float16* vsp = vs + vr * 128 + ((vc ^ vr) << 3);

  half8 kpre = *(const half8*)kgp;
  half8 vpre = *(const half8*)vgp;

  f32x4 lacc = {0.f, 0.f, 0.f, 0.f};
  f32x4 O0 = {0.f,0.f,0.f,0.f}, O1 = {0.f,0.f,0.f,0.f};

  for (int c0 = 0; c0 < 2048; c0 += 128) {
    *(half8*)ksp = kpre;
    *(half8*)vsp = vpre;
    __syncthreads();
    const int nxt = (c0 + 128 < 2048) ? c0 + 128 : 0;
    kpre = *(const half8*)(kgp + (size_t)nxt * 16);
    vpre = *(const half8*)(vgp + nxt);
#pragma unroll
    for (int hc = 0; hc < 2; ++hc) {
      f32x4 s[4];
#pragma unroll
      for (int i = 0; i < 4; ++i) {
        const int sub = hc * 4 + i;
        const half4 kf = *(const half4*)(ks + (sub * 16 + t) * KST_ +
                                         (g >> 1) * 8 + (g & 1) * 4);
        const f32x4 z = {0.f, 0.f, 0.f, 0.f};
        s[i] = __builtin_amdgcn_mfma_f32_16x16x16f16(kf, qf, z, 0, 0, 0);
      }
      half4 pf[4];
#pragma unroll
      for (int i = 0; i < 4; ++i) {
        const float p0 = fexp2(s[i][0]), p1 = fexp2(s[i][1]);
        const float p2 = fexp2(s[i][2]), p3 = fexp2(s[i][3]);
        lacc[0] += p0; lacc[1] += p1; lacc[2] += p2; lacc[3] += p3;
        pf[i][0] = (_Float16)p0; pf[i][1] = (_Float16)p1;
        pf[i][2] = (_Float16)p2; pf[i][3] = (_Float16)p3;
      }
#pragma unroll
      for (int i = 0; i < 4; ++i) {
        const int c = (hc * 4 + i) * 2 + (g >> 1);
        const half4 vf = *(const half4*)(vs + t * 128 + ((c ^ t) << 3) + (g & 1) * 4);
        if (i & 1) O1 = __builtin_amdgcn_mfma_f32_16x16x16f16(vf, pf[i], O1, 0, 0, 0);
        else       O0 = __builtin_amdgcn_mfma_f32_16x16x16f16(vf, pf[i], O0, 0, 0, 0);
      }
    }
    __syncthreads();
  }
  float l = lacc[0] + lacc[1] + lacc[2] + lacc[3];
  l += __shfl_xor(l, 16);
  l += __shfl_xor(l, 32);
  _Float16* aop = (kvh ? P.ao1 : P.ao0) +
                  ((size_t)(m * 2 + b) * N_ + q0 + t) * 64 + h * 16 + g * 4;
  half4 hv;
#pragma unroll
  for (int r = 0; r < 4; ++r) hv[r] = (_Float16)(O0[r] + O1[r]);
  *(half4*)aop = hv;
  if ((tid & 48) == 0)
    P.L[((size_t)(kvh * 3 + m) * 8 + bh) * N_ + q0 + t] = l;
}

// ---------------------------------------------------------------------------
// Wo projection + bias + residual -> d_out, fused GroupNorm stats.
// Stages ao0+ao1 (summed) in LDS; lane-uniform 1/(l0+l1) applied pre-MFMA.
// grid (64, 8, 3).
// ---------------------------------------------------------------------------
#define BS_ 72

__global__ __launch_bounds__(256) void wo_resid_kernel(TP P) {
  __shared__ _Float16 as[64 * BS_];
  const int m = blockIdx.z;
  const int b = blockIdx.y >> 2, cblk = blockIdx.y & 3;
  const int n0 = blockIdx.x * 64;
  const int tid = threadIdx.x;
  const int w = tid >> 6, g = (tid >> 4) & 3, t = tid & 15;
  const int c0 = cblk * 64 + w * 16;
  const size_t aob = ((size_t)(m * 2 + b) * N_) * 64;
  const _Float16* __restrict__ a0p = P.ao0 + aob;
  const _Float16* __restrict__ a1p = P.ao1 + aob;
  const int ar = tid >> 2, ac = (tid & 3) * 16;
  {
    const size_t off = (size_t)(n0 + ar) * 64 + ac;
    half8 s0 = *(const half8*)(a0p + off);
    half8 s1 = *(const half8*)(a0p + off + 8);
    const half8 u0 = *(const half8*)(a1p + off);
    const half8 u1 = *(const half8*)(a1p + off + 8);
    s0 += u0; s1 += u1;
    *(half8*)(as + ar * BS_ + ac) = s0;
    *(half8*)(as + ar * BS_ + ac + 8) = s1;
  }
  __syncthreads();
  const float* __restrict__ L0 = P.L + ((size_t)m * 8 + b * 4) * N_;
  const float* __restrict__ L1 = P.L + ((size_t)(3 + m) * 8 + b * 4) * N_;
  f32x4 acc[4] = {{0.f,0.f,0.f,0.f},{0.f,0.f,0.f,0.f},{0.f,0.f,0.f,0.f},{0.f,0.f,0.f,0.f}};
  const float* __restrict__ Wo = P.Wo[m] + (c0 + t) * 64;
#pragma unroll
  for (int kst = 0; kst < 2; ++kst) {
    const float4 w0 = *(const float4*)(Wo + kst * 32 + g * 8);
    const float4 w1 = *(const float4*)(Wo + kst * 32 + g * 8 + 4);
    half8 a;
    a[0] = (_Float16)w0.x; a[1] = (_Float16)w0.y;
    a[2] = (_Float16)w0.z; a[3] = (_Float16)w0.w;
    a[4] = (_Float16)w1.x; a[5] = (_Float16)w1.y;
    a[6] = (_Float16)w1.z; a[7] = (_Float16)w1.w;
    const int head = kst * 2 + (g >> 1);
#pragma unroll
    for (int i = 0; i < 4; ++i) {
      const int n = n0 + i * 16 + t;
      half8 bf = *(const half8*)(as + (i * 16 + t) * BS_ + kst * 32 + g * 8);
      const float ls = L0[(size_t)head * N_ + n] + L1[(size_t)head * N_ + n];
      const _Float16 hs = (_Float16)(1.0f / ls);
#pragma unroll
      for (int r = 0; r < 8; ++r) bf[r] *= hs;
      acc[i] = __builtin_amdgcn_mfma_f32_16x16x32_f16(a, bf, acc[i], 0, 0, 0);
    }
  }
  const float* __restrict__ X = P.feat[m] + (size_t)b * C_ * N_;
  float* outb = P.out + (size_t)m * B_ * C_ * N_ + (size_t)b * C_ * N_;
  float s = 0.f, s2 = 0.f;
#pragma unroll
  for (int i = 0; i < 4; ++i) {
    const int n = n0 + i * 16 + t;
#pragma unroll
    for (int r = 0; r < 4; ++r) {
      const int c = c0 + g * 4 + r;
      const float val = acc[i][r] + X[(size_t)c * N_ + n] + P.bo[m][c];
      outb[(size_t)c * N_ + n] = val;
      s += val;
      s2 += val * val;
    }
  }
#pragma unroll
  for (int off = 1; off < 64; off <<= 1) {
    s += __shfl_xor(s, off);
    s2 += __shfl_xor(s2, off);
  }
  if ((tid & 63) == 0) {
    const int group = cblk * 4 + w;
    float* st = P.stats + ((size_t)(m * 2 + b) * 16 + group) * 2;
    atomicAdd(st, s);
    atomicAdd(st + 1, s2);
  }
}

// ---------------------------------------------------------------------------
// GroupNorm normalize pass, 4 float4 per thread. grid (1536), block 256.
// ---------------------------------------------------------------------------
__global__ __launch_bounds__(256) void gn_final_kernel(TP P) {
  const size_t base = ((size_t)blockIdx.x * 256 + threadIdx.x) * 4;
#pragma unroll
  for (int it = 0; it < 4; ++it) {
    const size_t idx = base + (size_t)it * 1572864;
    const int m = (int)(idx >> 21);
    const int rem = (int)(idx & ((1u << 21) - 1));
    const int b = rem >> 20;
    const int c = (rem >> 12) & 255;
    const float* st = P.stats + ((size_t)(m * 2 + b) * 16 + (c >> 4)) * 2;
    const float mean = st[0] * (1.f / 65536.f);
    const float var = st[1] * (1.f / 65536.f) - mean * mean;
    const float rstd = rsqrtf(var + EPS_);
    const float ga = P.gm[m][c] * rstd, be = P.bt[m][c];
    float4 x = *(float4*)(P.out + idx);
    x.x = (x.x - mean) * ga + be;
    x.y = (x.y - mean) * ga + be;
    x.z = (x.z - mean) * ga + be;
    x.w = (x.w - mean) * ga + be;
    *(float4*)(P.out + idx) = x;
  }
}

// ---------------------------------------------------------------------------
extern "C" void kernel_launch(void* const* d_in, const int* in_sizes, int n_in,
                              void* d_out, int out_size, void* d_ws, size_t ws_size,
                              hipStream_t stream) {
  TP P;
  for (int m = 0; m < 3; ++m) {
    P.feat[m] = (const float*)d_in[m];
    const int base = 3 + m * 10;
    P.Wq[m] = (const float*)d_in[base + 0];
    P.bq[m] = (const float*)d_in[base + 1];
    P.Wk[m] = (const float*)d_in[base + 2];
    P.bk[m] = (const float*)d_in[base + 3];
    P.Wv[m] = (const float*)d_in[base + 4];
    P.bv[m] = (const float*)d_in[base + 5];
    P.Wo[m] = (const float*)d_in[base + 6];
    P.bo[m] = (const float*)d_in[base + 7];
    P.gm[m] = (const float*)d_in[base + 8];
    P.bt[m] = (const float*)d_in[base + 9];
  }
  _Float16* ws = (_Float16*)d_ws;
  const size_t SZ = 1572864;
  P.q16 = ws;
  P.k16 = ws + SZ;
  P.v16 = ws + 2 * SZ;
  P.ao0 = ws + 3 * SZ;
  P.ao1 = ws + 4 * SZ;
  P.L = (float*)(ws + 5 * SZ);            // 196,608 floats
  P.stats = (float*)(ws + 5 * SZ) + 196608;
  P.out = (float*)d_out;
  P.ctx0[0] = 1; P.ctx1[0] = 2;
  P.ctx0[1] = 0; P.ctx1[1] = 2;
  P.ctx0[2] = 0; P.ctx1[2] = 1;

  proj_fused_kernel<<<dim3(128, 2, 3), dim3(256), 0, stream>>>(P);
  attn_kernel<<<dim3(128, 8, 3), dim3(256), 0, stream>>>(P);
  wo_resid_kernel<<<dim3(64, 8, 3), dim3(256), 0, stream>>>(P);
  gn_final_kernel<<<dim3(1536), dim3(256), 0, stream>>>(P);
}